// Round 17
// baseline (90.241 us; speedup 1.0000x reference)
//
#include <hip/hip_runtime.h>
#include <math.h>

// Capsule dynamic routing v18 — fused, LDS-parked priors + W-dedup + full CU.
// R14-R16 verdict: the split's P-through-HBM (92MB write + 46MB read) is
// structurally bound at ~2.7TB/s uncore; K1 stuck at 46us across 3 fixes.
// v18 goes back to fused with every lesson applied:
//  - P parked in LDS as packed fp16 DURING the priors phase (73KB), read
//    back into 36 regs for routing. Each thread reads only its OWN writes:
//    no barrier, thread-linear layout [j][tid] -> 2-way banks (free).
//    LDS is purely a register-pressure relief valve: priors phase lives in
//    ~54 regs, routing in ~60 — both under the measured T=1024 grant of 64.
//  - G=2 via 8-lane groups: lanes q and q+4 read the SAME W float4 ->
//    coalescer merges -> per-CU W stream halves (5.9 -> 2.95 MB).
//  - T=1024, RPT=9 (v10's proven depth), 78KB LDS -> 2 blocks/CU
//    = 32 waves/CU (full occupancy).
//  - v16's proven routing: fused softmax (no max pass, Z folded), ONE
//    barrier/iter via parity double-buffered partials, NW=16 flat combine.
//
// x: [B=256, R=1152, I=8] f32 ; W: [C=10, R=1152, I=8, O=16] f32
// out: [B=256, C=10, O=16] f32
//
// One block per (c, b-pair). 1024 threads = 128 groups of 8 lanes; 16 waves.
// Group g owns rows r = g + j*128 (j=0..8); lane: q=t&3 o-quad,
// bsel=(t>>2)&1 batch.

#define C_CAPS 10
#define B_SZ   256
#define R_SZ   1152
#define I_SZ   8
#define O_SZ   16
#define T_THREADS 1024
#define NGROUP 128
#define RPT 9
#define NW 16

static __device__ __forceinline__ unsigned int pack2h(float a, float b) {
    const _Float16 ha = (_Float16)a, hb = (_Float16)b;
    const unsigned short ua = __builtin_bit_cast(unsigned short, ha);
    const unsigned short ub = __builtin_bit_cast(unsigned short, hb);
    return (unsigned int)ua | ((unsigned int)ub << 16);
}
static __device__ __forceinline__ float h2f(unsigned short u) {
    const _Float16 h = __builtin_bit_cast(_Float16, u);
    return (float)h;
}

__global__ __launch_bounds__(T_THREADS, 1) void capsule_kernel(
    const float* __restrict__ x,
    const float* __restrict__ w,
    float* __restrict__ out)
{
    const int c  = blockIdx.x >> 7;        // / (B/2)
    const int bb = blockIdx.x & 127;
    const int b0 = bb * 2;
    const int t = (int)threadIdx.x;
    const int lane = t & 63;
    const int wid = t >> 6;
    const int q    = t & 3;                // o-quad
    const int bsel = (t >> 2) & 1;         // batch select
    const int g    = t >> 3;               // group 0..127

    __shared__ uint2  Plds[RPT][T_THREADS];      // 73728 B, packed fp16 x4
    __shared__ float4 red_s[2][NW][2][4];        // 4096 B
    __shared__ float  red_z[2][NW][2];           // 256 B

    // ---- priors phase: P[bsel][r=g+j*128][q-quad] -> LDS (own slot) ----
    #pragma unroll
    for (int j = 0; j < RPT; ++j) {
        const int r = g + j * NGROUP;
        const float* xp = x + ((size_t)(b0 + bsel) * R_SZ + r) * I_SZ;
        const float4 xa = *(const float4*)(xp);        // q-lanes broadcast
        const float4 xb = *(const float4*)(xp + 4);
        const float xi[I_SZ] = {xa.x, xa.y, xa.z, xa.w, xb.x, xb.y, xb.z, xb.w};
        // lanes q and q+4 read the SAME address -> merged transaction
        const float* wr = w + ((size_t)c * R_SZ + r) * (I_SZ * O_SZ) + q * 4;
        float a0 = 0.f, a1 = 0.f, a2 = 0.f, a3 = 0.f;
        #pragma unroll
        for (int i = 0; i < I_SZ; ++i) {
            const float4 wv = *(const float4*)(wr + i * O_SZ);
            a0 = fmaf(xi[i], wv.x, a0);
            a1 = fmaf(xi[i], wv.y, a1);
            a2 = fmaf(xi[i], wv.z, a2);
            a3 = fmaf(xi[i], wv.w, a3);
        }
        uint2 pp;
        pp.x = pack2h(a0, a1);
        pp.y = pack2h(a2, a3);
        Plds[j][t] = pp;                   // thread-linear: 2-way banks, free
    }

    // ---- read back own P into registers (no barrier: own data) ----
    float Pr[RPT][4];
    #pragma unroll
    for (int j = 0; j < RPT; ++j) {
        const uint2 pp = Plds[j][t];
        Pr[j][0] = h2f((unsigned short)(pp.x & 0xffffu));
        Pr[j][1] = h2f((unsigned short)(pp.x >> 16));
        Pr[j][2] = h2f((unsigned short)(pp.y & 0xffffu));
        Pr[j][3] = h2f((unsigned short)(pp.y >> 16));
    }

    float logit[RPT];
    #pragma unroll
    for (int j = 0; j < RPT; ++j) logit[j] = 0.0f;

    float vq[4];

    for (int it = 0; it < 3; ++it) {
        const int pb = it & 1;
        // ---- fused exp + weighted-sum partials (no max pass; |logit|<=~40) ----
        float sa0 = 0.f, sa1 = 0.f, sa2 = 0.f, sa3 = 0.f, zp = 0.f;
        #pragma unroll
        for (int j = 0; j < RPT; ++j) {
            const float e = __expf(logit[j]);   // it==0: exp(0)=1 exactly
            zp += e;
            sa0 = fmaf(e, Pr[j][0], sa0);
            sa1 = fmaf(e, Pr[j][1], sa1);
            sa2 = fmaf(e, Pr[j][2], sa2);
            sa3 = fmaf(e, Pr[j][3], sa3);
        }
        // reduce across the wave's 8 groups (same (bsel,q) lanes): 3 steps
        #pragma unroll
        for (int m = 8; m <= 32; m <<= 1) {
            sa0 += __shfl_xor(sa0, m, 64);
            sa1 += __shfl_xor(sa1, m, 64);
            sa2 += __shfl_xor(sa2, m, 64);
            sa3 += __shfl_xor(sa3, m, 64);
            zp  += __shfl_xor(zp,  m, 64);
        }
        if (lane < 8) {
            red_s[pb][wid][lane >> 2][lane & 3] = make_float4(sa0, sa1, sa2, sa3);
            if ((lane & 3) == 0) red_z[pb][wid][lane >> 2] = zp;
        }
        __syncthreads();                       // the ONLY barrier this iter

        // ---- every thread combines the 16 wave partials (broadcast reads) ----
        float4 sf = red_s[pb][0][bsel][q];
        float Z = red_z[pb][0][bsel];
        #pragma unroll
        for (int ww = 1; ww < NW; ++ww) {
            const float4 rr = red_s[pb][ww][bsel][q];
            sf.x += rr.x; sf.y += rr.y; sf.z += rr.z; sf.w += rr.w;
            Z += red_z[pb][ww][bsel];
        }

        // ---- normalize + squash (normalize BEFORE squaring: overflow-safe) ----
        const float invZ = 1.0f / Z;
        const float u0 = sf.x * invZ, u1 = sf.y * invZ,
                    u2 = sf.z * invZ, u3 = sf.w * invZ;
        float nq = u0*u0 + u1*u1 + u2*u2 + u3*u3;
        nq += __shfl_xor(nq, 1, 64);           // masks 1,2 stay within bsel
        nq += __shfl_xor(nq, 2, 64);
        const float scale = nq / ((1.0f + nq) * sqrtf(nq));
        vq[0] = scale * u0; vq[1] = scale * u1;
        vq[2] = scale * u2; vq[3] = scale * u3;

        // ---- logit update (iters 0,1): logit[r] += P[r]·v ----
        if (it < 2) {
            #pragma unroll
            for (int j = 0; j < RPT; ++j) {
                float d = Pr[j][0]*vq[0] + Pr[j][1]*vq[1]
                        + Pr[j][2]*vq[2] + Pr[j][3]*vq[3];
                d += __shfl_xor(d, 1, 64);
                d += __shfl_xor(d, 2, 64);
                logit[j] += d;
            }
        }
        // no end-of-iter barrier: buf[pb] is rewritten only in iter it+2,
        // after barrier(it+1), which all threads pass only after finishing
        // this iter's reads. (v16-proven parity argument)
    }

    // ---- write out[b0+bsel, c, :]: threads 0..7 hold (bsel, quad) ----
    if (t < 8) {
        float* op = out + ((size_t)(b0 + (t >> 2)) * C_CAPS + c) * O_SZ + (t & 3) * 4;
        *(float4*)op = make_float4(vq[0], vq[1], vq[2], vq[3]);
    }
}

extern "C" void kernel_launch(void* const* d_in, const int* in_sizes, int n_in,
                              void* d_out, int out_size, void* d_ws, size_t ws_size,
                              hipStream_t stream) {
    const float* x = (const float*)d_in[0];
    const float* w = (const float*)d_in[1];
    float* out = (float*)d_out;
    dim3 grid(C_CAPS * (B_SZ / 2));
    dim3 block(T_THREADS);
    hipLaunchKernelGGL(capsule_kernel, grid, block, 0, stream, x, w, out);
}

// Round 18
// 55.567 us; speedup vs baseline: 1.6240x; 1.6240x over previous
//
#include <hip/hip_runtime.h>
#include <math.h>

// Capsule dynamic routing v19 — fused; TRUE G=2 fan-out + LDS-parked P + re-split routing.
// Cost model from R8-R17 (fits all data): wave VMEM dwordx4 ~16cyc at 4 lanes/cyc
// REGARDLESS of address dup (dedup never paid: v12/v13/v18). Only fewer VMEM
// instructions help. v19: each thread's W row-quad load feeds FMAs for BOTH
// batches (R10 fan-out, halves W instrs/batch); both P results parked in LDS
// fp16 (R18-proven clean); threads RE-PARTITIONED for routing (each handles one
// bsel, 18 rows, P re-read from LDS transiently) so no register blowup.
// Per-CU VMEM: 5 blk x 8 waves x 108 instr x 16cyc = 29us (v10 was 48).
// Routing: v16 single-barrier parity-buffered reduction (proven).
//
// x: [B=256, R=1152, I=8] f32 ; W: [C=10, R=1152, I=8, O=16] f32
// out: [B=256, C=10, O=16] f32
//
// One block per (c, b-pair). T=512, 8 waves; LDS ~76KB -> 2 blocks/CU.
// Priors: g=t>>2 (128 groups), q=t&3; rows r=g+j*128, j=0..8; both batches.
// Routing: g2=t>>3 (64 groups), bsel=(t>>2)&1, q2=t&3; rows r=g2+jj*64, jj=0..17.

#define C_CAPS 10
#define B_SZ   256
#define R_SZ   1152
#define I_SZ   8
#define O_SZ   16
#define T_THREADS 512
#define RPT_P 9
#define RPT_R 18
#define NW 8

static __device__ __forceinline__ unsigned int pack2h(float a, float b) {
    const _Float16 ha = (_Float16)a, hb = (_Float16)b;
    const unsigned short ua = __builtin_bit_cast(unsigned short, ha);
    const unsigned short ub = __builtin_bit_cast(unsigned short, hb);
    return (unsigned int)ua | ((unsigned int)ub << 16);
}
static __device__ __forceinline__ float h2f_lo(unsigned int u) {
    const _Float16 h = __builtin_bit_cast(_Float16, (unsigned short)(u & 0xffffu));
    return (float)h;
}
static __device__ __forceinline__ float h2f_hi(unsigned int u) {
    const _Float16 h = __builtin_bit_cast(_Float16, (unsigned short)(u >> 16));
    return (float)h;
}

__global__ __launch_bounds__(T_THREADS, 1) void capsule_kernel(
    const float* __restrict__ x,
    const float* __restrict__ w,
    float* __restrict__ out)
{
    const int c  = blockIdx.x >> 7;        // / (B/2)
    const int bb = blockIdx.x & 127;
    const int b0 = bb * 2;
    const int t = (int)threadIdx.x;
    const int lane = t & 63;
    const int wid = t >> 6;

    __shared__ uint2  Plds[RPT_P][2][T_THREADS];   // [j][bsel][priors-thread] 73728B
    __shared__ float4 red_s[2][NW][2][4];          // parity, wave, bsel, q
    __shared__ float  red_z[2][NW][2];

    // ================= priors phase: G=2 fan-out =================
    {
        const int g = t >> 2;              // 0..127
        const int q = t & 3;
        const float* xp0 = x + ((size_t)b0 * R_SZ + g) * I_SZ;
        const float* xp1 = xp0 + (size_t)R_SZ * I_SZ;
        const float* wr  = w + ((size_t)c * R_SZ + g) * (I_SZ * O_SZ) + q * 4;
        const size_t xstep = (size_t)128 * I_SZ;            // 128 rows
        const size_t wstep = (size_t)128 * I_SZ * O_SZ;

        #pragma unroll
        for (int j = 0; j < RPT_P; ++j) {
            const float4 x0a = *(const float4*)(xp0 + j * xstep);
            const float4 x0b = *(const float4*)(xp0 + j * xstep + 4);
            const float4 x1a = *(const float4*)(xp1 + j * xstep);
            const float4 x1b = *(const float4*)(xp1 + j * xstep + 4);
            const float xi0[I_SZ] = {x0a.x, x0a.y, x0a.z, x0a.w,
                                     x0b.x, x0b.y, x0b.z, x0b.w};
            const float xi1[I_SZ] = {x1a.x, x1a.y, x1a.z, x1a.w,
                                     x1b.x, x1b.y, x1b.z, x1b.w};
            const float* wj = wr + j * wstep;
            float a00=0.f, a01=0.f, a02=0.f, a03=0.f;
            float a10=0.f, a11=0.f, a12=0.f, a13=0.f;
            #pragma unroll
            for (int i = 0; i < I_SZ; ++i) {
                const float4 wv = *(const float4*)(wj + i * O_SZ);  // feeds 8 FMA
                a00 = fmaf(xi0[i], wv.x, a00);
                a01 = fmaf(xi0[i], wv.y, a01);
                a02 = fmaf(xi0[i], wv.z, a02);
                a03 = fmaf(xi0[i], wv.w, a03);
                a10 = fmaf(xi1[i], wv.x, a10);
                a11 = fmaf(xi1[i], wv.y, a11);
                a12 = fmaf(xi1[i], wv.z, a12);
                a13 = fmaf(xi1[i], wv.w, a13);
            }
            uint2 p0, p1;
            p0.x = pack2h(a00, a01); p0.y = pack2h(a02, a03);
            p1.x = pack2h(a10, a11); p1.y = pack2h(a12, a13);
            Plds[j][0][t] = p0;
            Plds[j][1][t] = p1;
        }
    }
    __syncthreads();     // routing reads other threads' parks

    // ================= routing phase: re-partitioned =================
    const int g2   = t >> 3;               // 0..63
    const int bsel = (t >> 2) & 1;
    const int q2   = t & 3;

    float logit[RPT_R];
    #pragma unroll
    for (int jj = 0; jj < RPT_R; ++jj) logit[jj] = 0.0f;

    float vq[4];

    for (int it = 0; it < 3; ++it) {
        const int pb = it & 1;
        // ---- fused exp + weighted-sum partials; P streamed from LDS ----
        float sa0 = 0.f, sa1 = 0.f, sa2 = 0.f, sa3 = 0.f, zp = 0.f;
        #pragma unroll
        for (int jj = 0; jj < RPT_R; ++jj) {
            // r = g2 + jj*64 ; priors slot: j = r>>7 = jj>>1,
            // tp = ((r&127)<<2)|q2 = ((g2 + (jj&1)*64)<<2)|q2
            const uint2 pp = Plds[jj >> 1][bsel][((g2 + ((jj & 1) << 6)) << 2) | q2];
            const float e = __expf(logit[jj]);   // it==0: exp(0)=1 exactly
            zp += e;
            sa0 = fmaf(e, h2f_lo(pp.x), sa0);
            sa1 = fmaf(e, h2f_hi(pp.x), sa1);
            sa2 = fmaf(e, h2f_lo(pp.y), sa2);
            sa3 = fmaf(e, h2f_hi(pp.y), sa3);
        }
        // reduce across the wave's 8 g2-values (masks 8,16,32)
        #pragma unroll
        for (int m = 8; m <= 32; m <<= 1) {
            sa0 += __shfl_xor(sa0, m, 64);
            sa1 += __shfl_xor(sa1, m, 64);
            sa2 += __shfl_xor(sa2, m, 64);
            sa3 += __shfl_xor(sa3, m, 64);
            zp  += __shfl_xor(zp,  m, 64);
        }
        if (lane < 8) {     // lane = bsel*4+q2 for the 8 writer lanes
            red_s[pb][wid][lane >> 2][lane & 3] = make_float4(sa0, sa1, sa2, sa3);
            if ((lane & 3) == 0) red_z[pb][wid][lane >> 2] = zp;
        }
        __syncthreads();                       // the ONLY barrier this iter

        // ---- all threads combine the 8 wave partials (broadcast reads) ----
        float4 sf = red_s[pb][0][bsel][q2];
        float Z = red_z[pb][0][bsel];
        #pragma unroll
        for (int ww = 1; ww < NW; ++ww) {
            const float4 rr = red_s[pb][ww][bsel][q2];
            sf.x += rr.x; sf.y += rr.y; sf.z += rr.z; sf.w += rr.w;
            Z += red_z[pb][ww][bsel];
        }

        // ---- normalize + squash (normalize BEFORE squaring: overflow-safe) ----
        const float invZ = 1.0f / Z;
        const float u0 = sf.x * invZ, u1 = sf.y * invZ,
                    u2 = sf.z * invZ, u3 = sf.w * invZ;
        float nq = u0*u0 + u1*u1 + u2*u2 + u3*u3;
        nq += __shfl_xor(nq, 1, 64);           // flip q2 bits only
        nq += __shfl_xor(nq, 2, 64);
        const float scale = nq / ((1.0f + nq) * sqrtf(nq));
        vq[0] = scale * u0; vq[1] = scale * u1;
        vq[2] = scale * u2; vq[3] = scale * u3;

        // ---- logit update (iters 0,1): logit[r] += P[r]·v ----
        if (it < 2) {
            #pragma unroll
            for (int jj = 0; jj < RPT_R; ++jj) {
                const uint2 pp = Plds[jj >> 1][bsel][((g2 + ((jj & 1) << 6)) << 2) | q2];
                float d = h2f_lo(pp.x)*vq[0] + h2f_hi(pp.x)*vq[1]
                        + h2f_lo(pp.y)*vq[2] + h2f_hi(pp.y)*vq[3];
                d += __shfl_xor(d, 1, 64);
                d += __shfl_xor(d, 2, 64);
                logit[jj] += d;
            }
        }
        // parity argument (v16-proven): buf[pb] is rewritten only in iter
        // it+2, after barrier(it+1) which follows all of this iter's reads.
    }

    // ---- write out[b0+bsel, c, :]: threads 0..7 hold (bsel, quad) ----
    if (t < 8) {
        float* op = out + ((size_t)(b0 + (t >> 2)) * C_CAPS + c) * O_SZ + (t & 3) * 4;
        *(float4*)op = make_float4(vq[0], vq[1], vq[2], vq[3]);
    }
}

extern "C" void kernel_launch(void* const* d_in, const int* in_sizes, int n_in,
                              void* d_out, int out_size, void* d_ws, size_t ws_size,
                              hipStream_t stream) {
    const float* x = (const float*)d_in[0];
    const float* w = (const float*)d_in[1];
    float* out = (float*)d_out;
    dim3 grid(C_CAPS * (B_SZ / 2));
    dim3 block(T_THREADS);
    hipLaunchKernelGGL(capsule_kernel, grid, block, 0, stream, x, w, out);
}

// Round 19
// 54.703 us; speedup vs baseline: 1.6497x; 1.0158x over previous
//
#include <hip/hip_runtime.h>
#include <math.h>

// Capsule dynamic routing v20 — v19 + conflict-free routing reads.
// R18: v19 won (55.6us) but SQ_LDS_BANK_CONFLICT=3.48M: routing slot index
// ((g2<<2)|q2) collapses 32 lanes onto 16 bank-pairs (~4-way on 90 reads).
// v20 re-maps ROUTING THREADS so reads are lane-linear: thread t ->
// (q2=t&3, g2=(t>>2)&63, bsel=t>>8); its row r=g2+jj*64 lives at park slot
// [jj>>1][bsel][(t&255)|((jj&1)<<8)] -> consecutive lanes read consecutive
// uint2 slots (thread-linear = conflict-free, v18-proven). Reduction:
// in-wave over masks 4..32 (g2 bits), waves 0-3 = bsel 0 / 4-7 = bsel 1,
// combine sums the 4 waves of own bsel. Park phase unchanged from v19.
//
// x: [B=256, R=1152, I=8] f32 ; W: [C=10, R=1152, I=8, O=16] f32
// out: [B=256, C=10, O=16] f32
//
// One block per (c, b-pair). T=512, 8 waves; LDS ~75KB -> 2 blocks/CU.
// Priors: g=t>>2 (128 groups), q=t&3; rows r=g+j*128, j=0..8; both batches.

#define C_CAPS 10
#define B_SZ   256
#define R_SZ   1152
#define I_SZ   8
#define O_SZ   16
#define T_THREADS 512
#define RPT_P 9
#define RPT_R 18
#define NW 8

static __device__ __forceinline__ unsigned int pack2h(float a, float b) {
    const _Float16 ha = (_Float16)a, hb = (_Float16)b;
    const unsigned short ua = __builtin_bit_cast(unsigned short, ha);
    const unsigned short ub = __builtin_bit_cast(unsigned short, hb);
    return (unsigned int)ua | ((unsigned int)ub << 16);
}
static __device__ __forceinline__ float h2f_lo(unsigned int u) {
    const _Float16 h = __builtin_bit_cast(_Float16, (unsigned short)(u & 0xffffu));
    return (float)h;
}
static __device__ __forceinline__ float h2f_hi(unsigned int u) {
    const _Float16 h = __builtin_bit_cast(_Float16, (unsigned short)(u >> 16));
    return (float)h;
}

__global__ __launch_bounds__(T_THREADS, 1) void capsule_kernel(
    const float* __restrict__ x,
    const float* __restrict__ w,
    float* __restrict__ out)
{
    const int c  = blockIdx.x >> 7;        // / (B/2)
    const int bb = blockIdx.x & 127;
    const int b0 = bb * 2;
    const int t = (int)threadIdx.x;
    const int lane = t & 63;
    const int wid = t >> 6;

    __shared__ uint2  Plds[RPT_P][2][T_THREADS];   // [j][bsel][park-thread] 73728B
    __shared__ float4 red_s[2][NW][4];             // parity, wave, q2
    __shared__ float  red_z[2][NW];

    // ================= priors phase: G=2 fan-out (v19, proven) =================
    {
        const int g = t >> 2;              // 0..127
        const int q = t & 3;
        const float* xp0 = x + ((size_t)b0 * R_SZ + g) * I_SZ;
        const float* xp1 = xp0 + (size_t)R_SZ * I_SZ;
        const float* wr  = w + ((size_t)c * R_SZ + g) * (I_SZ * O_SZ) + q * 4;
        const size_t xstep = (size_t)128 * I_SZ;
        const size_t wstep = (size_t)128 * I_SZ * O_SZ;

        #pragma unroll
        for (int j = 0; j < RPT_P; ++j) {
            const float4 x0a = *(const float4*)(xp0 + j * xstep);
            const float4 x0b = *(const float4*)(xp0 + j * xstep + 4);
            const float4 x1a = *(const float4*)(xp1 + j * xstep);
            const float4 x1b = *(const float4*)(xp1 + j * xstep + 4);
            const float xi0[I_SZ] = {x0a.x, x0a.y, x0a.z, x0a.w,
                                     x0b.x, x0b.y, x0b.z, x0b.w};
            const float xi1[I_SZ] = {x1a.x, x1a.y, x1a.z, x1a.w,
                                     x1b.x, x1b.y, x1b.z, x1b.w};
            const float* wj = wr + j * wstep;
            float a00=0.f, a01=0.f, a02=0.f, a03=0.f;
            float a10=0.f, a11=0.f, a12=0.f, a13=0.f;
            #pragma unroll
            for (int i = 0; i < I_SZ; ++i) {
                const float4 wv = *(const float4*)(wj + i * O_SZ);  // feeds 8 FMA
                a00 = fmaf(xi0[i], wv.x, a00);
                a01 = fmaf(xi0[i], wv.y, a01);
                a02 = fmaf(xi0[i], wv.z, a02);
                a03 = fmaf(xi0[i], wv.w, a03);
                a10 = fmaf(xi1[i], wv.x, a10);
                a11 = fmaf(xi1[i], wv.y, a11);
                a12 = fmaf(xi1[i], wv.z, a12);
                a13 = fmaf(xi1[i], wv.w, a13);
            }
            uint2 p0, p1;
            p0.x = pack2h(a00, a01); p0.y = pack2h(a02, a03);
            p1.x = pack2h(a10, a11); p1.y = pack2h(a12, a13);
            Plds[j][0][t] = p0;                 // thread-linear writes: free
            Plds[j][1][t] = p1;
        }
    }
    __syncthreads();     // routing reads other threads' parks

    // ================= routing phase: lane-linear LDS reads =================
    const int q2   = t & 3;
    const int bsel = t >> 8;               // waves 0-3: bsel 0; waves 4-7: bsel 1
    const int p_lo = t & 255;              // park-thread low index

    float logit[RPT_R];
    #pragma unroll
    for (int jj = 0; jj < RPT_R; ++jj) logit[jj] = 0.0f;

    float vq[4];

    for (int it = 0; it < 3; ++it) {
        const int pb = it & 1;
        // ---- fused exp + weighted-sum partials; P lane-linear from LDS ----
        float sa0 = 0.f, sa1 = 0.f, sa2 = 0.f, sa3 = 0.f, zp = 0.f;
        #pragma unroll
        for (int jj = 0; jj < RPT_R; ++jj) {
            const uint2 pp = Plds[jj >> 1][bsel][p_lo | ((jj & 1) << 8)];
            const float e = __expf(logit[jj]);   // it==0: exp(0)=1 exactly
            zp += e;
            sa0 = fmaf(e, h2f_lo(pp.x), sa0);
            sa1 = fmaf(e, h2f_hi(pp.x), sa1);
            sa2 = fmaf(e, h2f_lo(pp.y), sa2);
            sa3 = fmaf(e, h2f_hi(pp.y), sa3);
        }
        // reduce across the wave's 16 g2-values (lane bits 2-5): masks 4..32
        #pragma unroll
        for (int m = 4; m <= 32; m <<= 1) {
            sa0 += __shfl_xor(sa0, m, 64);
            sa1 += __shfl_xor(sa1, m, 64);
            sa2 += __shfl_xor(sa2, m, 64);
            sa3 += __shfl_xor(sa3, m, 64);
            zp  += __shfl_xor(zp,  m, 64);
        }
        if (lane < 4) red_s[pb][wid][lane] = make_float4(sa0, sa1, sa2, sa3);
        if (lane == 0) red_z[pb][wid] = zp;
        __syncthreads();                       // the ONLY barrier this iter

        // ---- combine own-bsel's 4 wave partials (broadcast reads) ----
        const int wbase = bsel << 2;
        float4 sf = red_s[pb][wbase][q2];
        float Z = red_z[pb][wbase];
        #pragma unroll
        for (int k = 1; k < 4; ++k) {
            const float4 rr = red_s[pb][wbase + k][q2];
            sf.x += rr.x; sf.y += rr.y; sf.z += rr.z; sf.w += rr.w;
            Z += red_z[pb][wbase + k];
        }

        // ---- normalize + squash (normalize BEFORE squaring: overflow-safe) ----
        const float invZ = 1.0f / Z;
        const float u0 = sf.x * invZ, u1 = sf.y * invZ,
                    u2 = sf.z * invZ, u3 = sf.w * invZ;
        float nq = u0*u0 + u1*u1 + u2*u2 + u3*u3;
        nq += __shfl_xor(nq, 1, 64);           // flip q2 bits only
        nq += __shfl_xor(nq, 2, 64);
        const float scale = nq / ((1.0f + nq) * sqrtf(nq));
        vq[0] = scale * u0; vq[1] = scale * u1;
        vq[2] = scale * u2; vq[3] = scale * u3;

        // ---- logit update (iters 0,1): logit[r] += P[r]·v ----
        if (it < 2) {
            #pragma unroll
            for (int jj = 0; jj < RPT_R; ++jj) {
                const uint2 pp = Plds[jj >> 1][bsel][p_lo | ((jj & 1) << 8)];
                float d = h2f_lo(pp.x)*vq[0] + h2f_hi(pp.x)*vq[1]
                        + h2f_lo(pp.y)*vq[2] + h2f_hi(pp.y)*vq[3];
                d += __shfl_xor(d, 1, 64);
                d += __shfl_xor(d, 2, 64);
                logit[jj] += d;
            }
        }
        // parity argument (v16-proven): buf[pb] is rewritten only in iter
        // it+2, after barrier(it+1) which follows all of this iter's reads.
    }

    // ---- write out[b0+bsel, c, :] — one thread per (bsel, q2) ----
    if ((t & 255) < 4) {                       // t = 0..3 (bsel 0), 256..259 (bsel 1)
        float* op = out + ((size_t)(b0 + bsel) * C_CAPS + c) * O_SZ + q2 * 4;
        *(float4*)op = make_float4(vq[0], vq[1], vq[2], vq[3]);
    }
}

extern "C" void kernel_launch(void* const* d_in, const int* in_sizes, int n_in,
                              void* d_out, int out_size, void* d_ws, size_t ws_size,
                              hipStream_t stream) {
    const float* x = (const float*)d_in[0];
    const float* w = (const float*)d_in[1];
    float* out = (float*)d_out;
    dim3 grid(C_CAPS * (B_SZ / 2));
    dim3 block(T_THREADS);
    hipLaunchKernelGGL(capsule_kernel, grid, block, 0, stream, x, w, out);
}